// Round 2
// baseline (709.832 us; speedup 1.0000x reference)
//
#include <hip/hip_runtime.h>

// Problem constants
#define B_     32
#define NOTES_ 78
#define T_     128
#define IN_    80
#define H_     128
#define G4_    512            // 4*H
#define NSEQ_  (B_*NOTES_)    // 2496
#define MBLK   16             // sequences per block (stage 1)
#define NBLK1  (NSEQ_/MBLK)   // 156
#define SEQ2_  (B_*T_)        // 4096 note-LSTM sequences

typedef __attribute__((ext_vector_type(8))) short short8;   // 8 x bf16 (4 VGPRs)
typedef __attribute__((ext_vector_type(4))) float f32x4;

__device__ __forceinline__ float bf2f(unsigned short v) {
    unsigned u = ((unsigned)v) << 16; float f; __builtin_memcpy(&f, &u, 4); return f;
}
__device__ __forceinline__ unsigned short f2bf(float f) {
    unsigned u; __builtin_memcpy(&u, &f, 4);
    u += 0x7fffu + ((u >> 16) & 1u);          // RNE
    return (unsigned short)(u >> 16);
}
__device__ __forceinline__ short8 pack8(const float* p) {
    short8 r;
    #pragma unroll
    for (int k = 0; k < 8; ++k) r[k] = (short)f2bf(p[k]);
    return r;
}
__device__ __forceinline__ float sigm(float x)  { return 1.f / (1.f + __expf(-x)); }
__device__ __forceinline__ float tanh_(float x) { return 2.f / (1.f + __expf(-2.f*x)) - 1.f; }

// ---------------------------------------------------------------------------
// Stage 1: time LSTM. One block owns MBLK=16 sequences for all T=128 steps.
// f32 inputs; weights converted once to bf16 MFMA B-fragments in registers;
// h round-trips through LDS as bf16; c state in f32 registers.
// Output th written bf16 in [B][T][NOTES][H] layout (what stage 2 wants).
// ---------------------------------------------------------------------------
__global__ __launch_bounds__(256, 1) void time_lstm_kernel(
    const float* __restrict__ x,     // [B][NOTES][T][IN] f32
    const float* __restrict__ Wih,   // [512][80]  f32
    const float* __restrict__ Whh,   // [512][128] f32
    const float* __restrict__ bih,   // [512] f32
    const float* __restrict__ bhh,   // [512] f32
    unsigned short* __restrict__ th) // [B][T][NOTES][H] bf16 (ws)
{
    // sG: gate accumulators, transposed [col 512][m 16 + pad 4] f32 (40 KB)
    __shared__ float sG[G4_ * 20];
    // sH: h state bf16, [m 16][H 128 + pad 8] -> stride 136
    __shared__ unsigned short sH[MBLK * 136];

    const int tid  = threadIdx.x;
    const int wave = tid >> 6, lane = tid & 63;
    const int m16  = lane & 15, quad = lane >> 4;
    const int seq0 = blockIdx.x * MBLK;
    const int ncol0 = wave * 128;     // wave w owns gate columns [128w, 128w+128)

    for (int i = tid; i < MBLK * 136; i += 256) sH[i] = 0;   // h0 = 0

    // ---- preload weight B-fragments into registers (once), f32 -> bf16 ----
    // B[k][n] = W[n][k]; lane holds k = quad*8 + j (j=0..7), n = tile*16 + m16.
    short8 wf[3][8];   // Wih: K padded 80 -> 96
    short8 hf[4][8];   // Whh: K = 128
    #pragma unroll
    for (int nt = 0; nt < 8; ++nt) {
        const int n = ncol0 + nt * 16 + m16;
        #pragma unroll
        for (int kt = 0; kt < 3; ++kt) {
            const int k = kt * 32 + quad * 8;
            if (k < IN_) wf[kt][nt] = pack8(Wih + n * IN_ + k);
            else         wf[kt][nt] = (short8){0,0,0,0,0,0,0,0};
        }
        #pragma unroll
        for (int kt = 0; kt < 4; ++kt) {
            const int k = kt * 32 + quad * 8;
            hf[kt][nt] = pack8(Whh + n * H_ + k);
        }
    }

    // ---- elementwise mapping: this thread owns column j, rows mb..mb+7 ----
    const int j  = tid & 127;
    const int mb = (tid >> 7) * 8;
    const float b_i = bih[      j] + bhh[      j];
    const float b_f = bih[128 + j] + bhh[128 + j];
    const float b_g = bih[256 + j] + bhh[256 + j];
    const float b_o = bih[384 + j] + bhh[384 + j];
    float    cst[8];
    unsigned obase[8];
    #pragma unroll
    for (int mm = 0; mm < 8; ++mm) {
        cst[mm] = 0.f;
        const int sq = seq0 + mb + mm;
        const int bb = sq / NOTES_;
        const int nn = sq - bb * NOTES_;
        obase[mm] = (unsigned)bb * (T_ * NOTES_ * H_) + (unsigned)nn * H_ + (unsigned)j;
    }

    const float* xrow = x + (size_t)(seq0 + m16) * T_ * IN_;

    __syncthreads();

    for (int t = 0; t < T_; ++t) {
        // A-fragments: A[m][k], m = m16, k = quad*8 + j  (f32 -> bf16)
        const float* xp = xrow + t * IN_;
        short8 ax0 = pack8(xp + quad * 8);
        short8 ax1 = pack8(xp + 32 + quad * 8);
        short8 ax2 = (quad < 2) ? pack8(xp + 64 + quad * 8)
                                : (short8){0,0,0,0,0,0,0,0};
        short8 ah[4];
        #pragma unroll
        for (int kt = 0; kt < 4; ++kt)
            ah[kt] = *(const short8*)(sH + m16 * 136 + kt * 32 + quad * 8);

        f32x4 acc[8];
        #pragma unroll
        for (int nt = 0; nt < 8; ++nt) {
            acc[nt] = (f32x4){0.f, 0.f, 0.f, 0.f};
            acc[nt] = __builtin_amdgcn_mfma_f32_16x16x32_bf16(ax0, wf[0][nt], acc[nt], 0, 0, 0);
            acc[nt] = __builtin_amdgcn_mfma_f32_16x16x32_bf16(ax1, wf[1][nt], acc[nt], 0, 0, 0);
            acc[nt] = __builtin_amdgcn_mfma_f32_16x16x32_bf16(ax2, wf[2][nt], acc[nt], 0, 0, 0);
            #pragma unroll
            for (int kt = 0; kt < 4; ++kt)
                acc[nt] = __builtin_amdgcn_mfma_f32_16x16x32_bf16(ah[kt], hf[kt][nt], acc[nt], 0, 0, 0);
        }

        // C/D layout: col = lane&15, row = quad*4 + reg  ->  sG[c][row] b128 store
        #pragma unroll
        for (int nt = 0; nt < 8; ++nt) {
            const int c = ncol0 + nt * 16 + m16;
            *(f32x4*)(sG + c * 20 + quad * 4) = acc[nt];
        }
        __syncthreads();

        // ---- fused gate elementwise: c fp32 in regs, h -> bf16 (LDS + global)
        const float* gi_p = sG + (0   + j) * 20 + mb;
        const float* gf_p = sG + (128 + j) * 20 + mb;
        const float* gg_p = sG + (256 + j) * 20 + mb;
        const float* go_p = sG + (384 + j) * 20 + mb;
        f32x4 vi0 = *(const f32x4*)(gi_p), vi1 = *(const f32x4*)(gi_p + 4);
        f32x4 vf0 = *(const f32x4*)(gf_p), vf1 = *(const f32x4*)(gf_p + 4);
        f32x4 vg0 = *(const f32x4*)(gg_p), vg1 = *(const f32x4*)(gg_p + 4);
        f32x4 vo0 = *(const f32x4*)(go_p), vo1 = *(const f32x4*)(go_p + 4);
        #pragma unroll
        for (int mm = 0; mm < 8; ++mm) {
            const float gi = ((mm < 4) ? vi0[mm] : vi1[mm - 4]) + b_i;
            const float gf = ((mm < 4) ? vf0[mm] : vf1[mm - 4]) + b_f;
            const float gg = ((mm < 4) ? vg0[mm] : vg1[mm - 4]) + b_g;
            const float go = ((mm < 4) ? vo0[mm] : vo1[mm - 4]) + b_o;
            const float cf = sigm(gf) * cst[mm] + sigm(gi) * tanh_(gg);
            cst[mm] = cf;
            const float h = sigm(go) * tanh_(cf);
            const unsigned short hv = f2bf(h);
            sH[(mb + mm) * 136 + j] = hv;
            th[obase[mm] + (unsigned)t * (NOTES_ * H_)] = hv;
        }
        __syncthreads();
    }
}

// ---------------------------------------------------------------------------
// Stage 2: note LSTM (H=128 -> NH=2), one wave per (b,t) sequence, 78 steps.
// Lane l: gate g = l>>3 (order i0,i1,f0,f1,g0,g1,o0,o1), k-chunk kc = l&7.
// ---------------------------------------------------------------------------
__global__ __launch_bounds__(256) void note_lstm_kernel(
    const unsigned short* __restrict__ th,    // [B][T][NOTES][H] bf16
    const float* __restrict__ Wih,            // [8][128] f32
    const float* __restrict__ Whh,            // [8][2]   f32
    const float* __restrict__ bih,            // [8] f32
    const float* __restrict__ bhh,            // [8] f32
    float* __restrict__ out)                  // [B][T][156] f32
{
    const int tid  = threadIdx.x;
    const int wave = tid >> 6, lane = tid & 63;
    const int q    = blockIdx.x * 4 + wave;   // (b,t) sequence id, 0..4095
    const int g    = lane >> 3, kc = lane & 7;

    float wih[16];
    #pragma unroll
    for (int kk = 0; kk < 16; ++kk) wih[kk] = Wih[g * H_ + kc * 16 + kk];
    const float whh0 = Whh[g * 2 + 0];
    const float whh1 = Whh[g * 2 + 1];
    const float bsum = bih[g] + bhh[g];

    const unsigned short* xb = th + (size_t)q * (NOTES_ * H_) + kc * 16;
    float* ob = out + (size_t)q * (NOTES_ * 2);

    float h0 = 0.f, h1 = 0.f, c0 = 0.f, c1 = 0.f;
    for (int n = 0; n < NOTES_; ++n) {
        const unsigned short* xp = xb + n * H_;
        short8 xa = *(const short8*)(xp);
        short8 xc = *(const short8*)(xp + 8);
        float s = 0.f;
        #pragma unroll
        for (int kk = 0; kk < 8; ++kk) s += wih[kk]     * bf2f((unsigned short)xa[kk]);
        #pragma unroll
        for (int kk = 0; kk < 8; ++kk) s += wih[kk + 8] * bf2f((unsigned short)xc[kk]);
        // reduce the 8 k-chunks of this gate
        s += __shfl_xor(s, 1);
        s += __shfl_xor(s, 2);
        s += __shfl_xor(s, 4);
        const float gv = s + bsum + whh0 * h0 + whh1 * h1;
        // gather all 8 gate values (lane 8*g holds gate g's sum)
        const float gi0 = __shfl(gv, 0),  gi1 = __shfl(gv, 8);
        const float gf0 = __shfl(gv, 16), gf1 = __shfl(gv, 24);
        const float gg0 = __shfl(gv, 32), gg1 = __shfl(gv, 40);
        const float go0 = __shfl(gv, 48), go1 = __shfl(gv, 56);
        c0 = sigm(gf0) * c0 + sigm(gi0) * tanh_(gg0);
        c1 = sigm(gf1) * c1 + sigm(gi1) * tanh_(gg1);
        h0 = sigm(go0) * tanh_(c0);
        h1 = sigm(go1) * tanh_(c1);
        if (lane == 0) {
            ob[n * 2 + 0] = h0;
            ob[n * 2 + 1] = h1;
        }
    }
}

extern "C" void kernel_launch(void* const* d_in, const int* in_sizes, int n_in,
                              void* d_out, int out_size, void* d_ws, size_t ws_size,
                              hipStream_t stream) {
    const float* x     = (const float*)d_in[0];
    const float* Wih_t = (const float*)d_in[1];
    const float* Whh_t = (const float*)d_in[2];
    const float* bih_t = (const float*)d_in[3];
    const float* bhh_t = (const float*)d_in[4];
    const float* Wih_n = (const float*)d_in[5];
    const float* Whh_n = (const float*)d_in[6];
    const float* bih_n = (const float*)d_in[7];
    const float* bhh_n = (const float*)d_in[8];
    float* out = (float*)d_out;
    unsigned short* th = (unsigned short*)d_ws;   // NSEQ_*T_*H_ bf16 = ~82 MB

    time_lstm_kernel<<<NBLK1, 256, 0, stream>>>(x, Wih_t, Whh_t, bih_t, bhh_t, th);
    note_lstm_kernel<<<SEQ2_ / 4, 256, 0, stream>>>(th, Wih_n, Whh_n, bih_n, bhh_n, out);
}

// Round 3
// 664.571 us; speedup vs baseline: 1.0681x; 1.0681x over previous
//
#include <hip/hip_runtime.h>

// Problem constants
#define B_     32
#define NOTES_ 78
#define T_     128
#define IN_    80
#define H_     128
#define G4_    512            // 4*H
#define NSEQ_  (B_*NOTES_)    // 2496
#define MBLK   16             // sequences per block (stage 1)
#define NBLK1  (NSEQ_/MBLK)   // 156
#define SEQ2_  (B_*T_)        // 4096 note-LSTM sequences
#define NROWS  (SEQ2_*NOTES_) // 319488 rows of th

typedef __attribute__((ext_vector_type(8))) short short8;   // 8 x bf16 (4 VGPRs)
typedef __attribute__((ext_vector_type(4))) float f32x4;

__device__ __forceinline__ float bf2f(unsigned short v) {
    unsigned u = ((unsigned)v) << 16; float f; __builtin_memcpy(&f, &u, 4); return f;
}
__device__ __forceinline__ unsigned short f2bf(float f) {
    unsigned u; __builtin_memcpy(&u, &f, 4);
    u += 0x7fffu + ((u >> 16) & 1u);          // RNE
    return (unsigned short)(u >> 16);
}
__device__ __forceinline__ short8 pack8(const float* p) {
    short8 r;
    #pragma unroll
    for (int k = 0; k < 8; ++k) r[k] = (short)f2bf(p[k]);
    return r;
}
__device__ __forceinline__ float sigm(float x)  { return 1.f / (1.f + __expf(-x)); }
__device__ __forceinline__ float tanh_(float x) { return 2.f / (1.f + __expf(-2.f*x)) - 1.f; }

// ---------------------------------------------------------------------------
// Stage 1: time LSTM. One block (8 waves) owns MBLK=16 sequences for all T
// steps. Each wave owns 64 gate columns -> 28 weight frags = 112 VGPRs/wave
// (no spills; 2 waves/SIMD for latency hiding). h round-trips through LDS.
// ---------------------------------------------------------------------------
__global__ __launch_bounds__(512, 2) void time_lstm_kernel(
    const float* __restrict__ x,     // [B][NOTES][T][IN] f32
    const float* __restrict__ Wih,   // [512][80]  f32
    const float* __restrict__ Whh,   // [512][128] f32
    const float* __restrict__ bih,   // [512] f32
    const float* __restrict__ bhh,   // [512] f32
    unsigned short* __restrict__ th) // [B][T][NOTES][H] bf16 (ws)
{
    __shared__ float sG[G4_ * 20];          // gate acc, [col 512][row 16 + pad 4]
    __shared__ unsigned short sH[MBLK * 136];

    const int tid  = threadIdx.x;
    const int wave = tid >> 6, lane = tid & 63;
    const int m16  = lane & 15, quad = lane >> 4;
    const int seq0 = blockIdx.x * MBLK;
    const int ncol0 = wave * 64;            // wave w owns gate cols [64w, 64w+64)

    for (int i = tid; i < MBLK * 136; i += 512) sH[i] = 0;   // h0 = 0

    // ---- weight B-fragments (f32 -> bf16), 28 frags/wave ----
    short8 wf[3][4];   // Wih: K padded 80 -> 96
    short8 hf[4][4];   // Whh: K = 128
    #pragma unroll
    for (int nt = 0; nt < 4; ++nt) {
        const int n = ncol0 + nt * 16 + m16;
        #pragma unroll
        for (int kt = 0; kt < 3; ++kt) {
            const int k = kt * 32 + quad * 8;
            if (k < IN_) wf[kt][nt] = pack8(Wih + n * IN_ + k);
            else         wf[kt][nt] = (short8){0,0,0,0,0,0,0,0};
        }
        #pragma unroll
        for (int kt = 0; kt < 4; ++kt) {
            const int k = kt * 32 + quad * 8;
            hf[kt][nt] = pack8(Whh + n * H_ + k);
        }
    }

    // ---- elementwise mapping: thread owns h-col j, rows mb..mb+3 ----
    const int j  = tid & 127;
    const int mb = (tid >> 7) * 4;
    const float b_i = bih[      j] + bhh[      j];
    const float b_f = bih[128 + j] + bhh[128 + j];
    const float b_g = bih[256 + j] + bhh[256 + j];
    const float b_o = bih[384 + j] + bhh[384 + j];
    float    cst[4];
    unsigned obase[4];
    #pragma unroll
    for (int mm = 0; mm < 4; ++mm) {
        cst[mm] = 0.f;
        const int sq = seq0 + mb + mm;
        const int bb = sq / NOTES_;
        const int nn = sq - bb * NOTES_;
        obase[mm] = (unsigned)bb * (T_ * NOTES_ * H_) + (unsigned)nn * H_ + (unsigned)j;
    }

    const float* xrow = x + (size_t)(seq0 + m16) * T_ * IN_;

    __syncthreads();

    for (int t = 0; t < T_; ++t) {
        // A-fragments (shared across waves; redundant loads served by L1)
        const float* xp = xrow + t * IN_;
        short8 ax0 = pack8(xp + quad * 8);
        short8 ax1 = pack8(xp + 32 + quad * 8);
        short8 ax2 = (quad < 2) ? pack8(xp + 64 + quad * 8)
                                : (short8){0,0,0,0,0,0,0,0};
        short8 ah[4];
        #pragma unroll
        for (int kt = 0; kt < 4; ++kt)
            ah[kt] = *(const short8*)(sH + m16 * 136 + kt * 32 + quad * 8);

        f32x4 acc[4];
        #pragma unroll
        for (int nt = 0; nt < 4; ++nt) {
            acc[nt] = (f32x4){0.f, 0.f, 0.f, 0.f};
            acc[nt] = __builtin_amdgcn_mfma_f32_16x16x32_bf16(ax0, wf[0][nt], acc[nt], 0, 0, 0);
            acc[nt] = __builtin_amdgcn_mfma_f32_16x16x32_bf16(ax1, wf[1][nt], acc[nt], 0, 0, 0);
            acc[nt] = __builtin_amdgcn_mfma_f32_16x16x32_bf16(ax2, wf[2][nt], acc[nt], 0, 0, 0);
            #pragma unroll
            for (int kt = 0; kt < 4; ++kt)
                acc[nt] = __builtin_amdgcn_mfma_f32_16x16x32_bf16(ah[kt], hf[kt][nt], acc[nt], 0, 0, 0);
        }

        // C/D layout: col = lane&15, row = quad*4 + reg
        #pragma unroll
        for (int nt = 0; nt < 4; ++nt) {
            const int c = ncol0 + nt * 16 + m16;
            *(f32x4*)(sG + c * 20 + quad * 4) = acc[nt];
        }
        __syncthreads();

        // fused gate elementwise: c fp32 in regs, h -> bf16 (LDS + global)
        f32x4 vi = *(const f32x4*)(sG + (0   + j) * 20 + mb);
        f32x4 vf = *(const f32x4*)(sG + (128 + j) * 20 + mb);
        f32x4 vg = *(const f32x4*)(sG + (256 + j) * 20 + mb);
        f32x4 vo = *(const f32x4*)(sG + (384 + j) * 20 + mb);
        #pragma unroll
        for (int mm = 0; mm < 4; ++mm) {
            const float gi = vi[mm] + b_i;
            const float gf = vf[mm] + b_f;
            const float gg = vg[mm] + b_g;
            const float go = vo[mm] + b_o;
            const float cf = sigm(gf) * cst[mm] + sigm(gi) * tanh_(gg);
            cst[mm] = cf;
            const float h = sigm(go) * tanh_(cf);
            const unsigned short hv = f2bf(h);
            sH[(mb + mm) * 136 + j] = hv;
            th[obase[mm] + (unsigned)t * (NOTES_ * H_)] = hv;
        }
        __syncthreads();
    }
}

// ---------------------------------------------------------------------------
// Phase C: Gn[row][g] = th[row]·Wih_n[g] + bih_n[g] + bhh_n[g]   (row = (b,t,n))
// Wave: lane = g*8 + kc; one row per iteration; 3-step xor reduce over kc.
// Memory-bound streaming of th (82 MB).
// ---------------------------------------------------------------------------
__global__ __launch_bounds__(256) void gn_kernel(
    const unsigned short* __restrict__ th,    // [NROWS][128] bf16
    const float* __restrict__ Wih,            // [8][128] f32
    const float* __restrict__ bih,            // [8] f32
    const float* __restrict__ bhh,            // [8] f32
    float* __restrict__ Gn)                   // [NROWS][8] f32
{
    const int tid  = threadIdx.x;
    const int lane = tid & 63;
    const int g    = lane >> 3, kc = lane & 7;
    const int wv   = blockIdx.x * 4 + (tid >> 6);
    const int nw   = gridDim.x * 4;

    float w[16];
    #pragma unroll
    for (int k = 0; k < 16; ++k) w[k] = Wih[g * H_ + kc * 16 + k];
    const float bsum = bih[g] + bhh[g];

    for (int row = wv; row < NROWS; row += nw) {
        const unsigned short* p = th + (size_t)row * H_ + kc * 16;
        short8 a = *(const short8*)(p);
        short8 b = *(const short8*)(p + 8);
        float s = 0.f;
        #pragma unroll
        for (int k = 0; k < 8; ++k) s += w[k]     * bf2f((unsigned short)a[k]);
        #pragma unroll
        for (int k = 0; k < 8; ++k) s += w[k + 8] * bf2f((unsigned short)b[k]);
        s += __shfl_xor(s, 1);
        s += __shfl_xor(s, 2);
        s += __shfl_xor(s, 4);
        if (kc == 0) Gn[(size_t)row * 8 + g] = s + bsum;
    }
}

// ---------------------------------------------------------------------------
// Phase D: note-LSTM recurrence on precomputed pre-activations.
// One thread per (b,t) sequence; 78 tiny steps.
// Gate order g: 0,1=i  2,3=f  4,5=g  6,7=o  (NH=2 interleaved)
// ---------------------------------------------------------------------------
__global__ __launch_bounds__(256) void note_out_kernel(
    const float* __restrict__ Gn,    // [SEQ2_][NOTES][8] f32
    const float* __restrict__ Whh,   // [8][2] f32
    float* __restrict__ out)         // [B][T][156] f32
{
    const int q = blockIdx.x * 256 + threadIdx.x;
    if (q >= SEQ2_) return;

    float w0[8], w1[8];
    #pragma unroll
    for (int g = 0; g < 8; ++g) { w0[g] = Whh[g * 2]; w1[g] = Whh[g * 2 + 1]; }

    const float* gp = Gn + (size_t)q * (NOTES_ * 8);
    float* op = out + (size_t)q * (NOTES_ * 2);

    float h0 = 0.f, h1 = 0.f, c0 = 0.f, c1 = 0.f;
    for (int n = 0; n < NOTES_; ++n) {
        f32x4 ga = *(const f32x4*)(gp + n * 8);
        f32x4 gb = *(const f32x4*)(gp + n * 8 + 4);
        const float i0 = ga[0] + w0[0] * h0 + w1[0] * h1;
        const float i1 = ga[1] + w0[1] * h0 + w1[1] * h1;
        const float f0 = ga[2] + w0[2] * h0 + w1[2] * h1;
        const float f1 = ga[3] + w0[3] * h0 + w1[3] * h1;
        const float g0 = gb[0] + w0[4] * h0 + w1[4] * h1;
        const float g1 = gb[1] + w0[5] * h0 + w1[5] * h1;
        const float o0 = gb[2] + w0[6] * h0 + w1[6] * h1;
        const float o1 = gb[3] + w0[7] * h0 + w1[7] * h1;
        c0 = sigm(f0) * c0 + sigm(i0) * tanh_(g0);
        c1 = sigm(f1) * c1 + sigm(i1) * tanh_(g1);
        h0 = sigm(o0) * tanh_(c0);
        h1 = sigm(o1) * tanh_(c1);
        op[n * 2 + 0] = h0;
        op[n * 2 + 1] = h1;
    }
}

extern "C" void kernel_launch(void* const* d_in, const int* in_sizes, int n_in,
                              void* d_out, int out_size, void* d_ws, size_t ws_size,
                              hipStream_t stream) {
    const float* x     = (const float*)d_in[0];
    const float* Wih_t = (const float*)d_in[1];
    const float* Whh_t = (const float*)d_in[2];
    const float* bih_t = (const float*)d_in[3];
    const float* bhh_t = (const float*)d_in[4];
    const float* Wih_n = (const float*)d_in[5];
    const float* Whh_n = (const float*)d_in[6];
    const float* bih_n = (const float*)d_in[7];
    const float* bhh_n = (const float*)d_in[8];
    float* out = (float*)d_out;

    unsigned short* th = (unsigned short*)d_ws;            // 81.8 MB bf16
    float* Gn = (float*)((char*)d_ws + (size_t)NROWS * H_ * 2);  // +10.2 MB f32

    time_lstm_kernel<<<NBLK1, 512, 0, stream>>>(x, Wih_t, Whh_t, bih_t, bhh_t, th);
    gn_kernel<<<4096, 256, 0, stream>>>(th, Wih_n, bih_n, bhh_n, Gn);
    note_out_kernel<<<SEQ2_ / 256, 256, 0, stream>>>(Gn, Whh_n, out);
}

// Round 4
// 524.502 us; speedup vs baseline: 1.3533x; 1.2671x over previous
//
#include <hip/hip_runtime.h>

// Problem constants
#define B_     32
#define NOTES_ 78
#define T_     128
#define IN_    80
#define H_     128
#define G4_    512            // 4*H
#define NSEQ_  (B_*NOTES_)    // 2496
#define MBLK   16             // sequences per block (stage 1)
#define NBLK1  (NSEQ_/MBLK)   // 156
#define SEQ2_  (B_*T_)        // 4096 note-LSTM sequences
#define NROWS  (SEQ2_*NOTES_) // 319488 rows of th
#define XN8    (NSEQ_*T_*IN_/8) // 3,194,880 groups of 8 x-elements

typedef __attribute__((ext_vector_type(8))) short short8;   // 8 x bf16 (4 VGPRs)
typedef __attribute__((ext_vector_type(4))) float f32x4;

__device__ __forceinline__ float bf2f(unsigned short v) {
    unsigned u = ((unsigned)v) << 16; float f; __builtin_memcpy(&f, &u, 4); return f;
}
__device__ __forceinline__ unsigned short f2bf(float f) {
    unsigned u; __builtin_memcpy(&u, &f, 4);
    u += 0x7fffu + ((u >> 16) & 1u);          // RNE
    return (unsigned short)(u >> 16);
}
__device__ __forceinline__ short8 pack8(const float* p) {
    short8 r;
    #pragma unroll
    for (int k = 0; k < 8; ++k) r[k] = (short)f2bf(p[k]);
    return r;
}
__device__ __forceinline__ float sigm(float x)  { return 1.f / (1.f + __expf(-x)); }
__device__ __forceinline__ float tanh_(float x) { return 2.f / (1.f + __expf(-2.f*x)) - 1.f; }

// ---------------------------------------------------------------------------
// Phase A: convert x f32 -> bf16 (memory-bound, ~150 MB traffic)
// ---------------------------------------------------------------------------
__global__ __launch_bounds__(256) void xcvt_kernel(
    const float* __restrict__ x, unsigned short* __restrict__ xb)
{
    const int i = blockIdx.x * 256 + threadIdx.x;
    if (i < XN8) {
        short8 v = pack8(x + (size_t)i * 8);
        *(short8*)(xb + (size_t)i * 8) = v;
    }
}

// ---------------------------------------------------------------------------
// Phase B: time LSTM. One block (16 waves, 1024 thr) owns MBLK=16 sequences
// for all T steps. Each wave owns 32 gate columns -> 14 weight frags =
// 56 VGPRs; launch_bounds(1024,4) targets <=128 VGPR -> 4 waves/SIMD.
// x(t+1) prefetched before barrier#1; th store issued after barrier#2 so its
// vmcnt drain overlaps the next step's MFMA phase.
// ---------------------------------------------------------------------------
template<bool XB16>
__global__ __launch_bounds__(1024, 4) void time_lstm_kernel(
    const void* __restrict__ xin,    // [NSEQ][T][IN] bf16 (XB16) or f32
    const float* __restrict__ Wih,   // [512][80]  f32
    const float* __restrict__ Whh,   // [512][128] f32
    const float* __restrict__ bih,   // [512] f32
    const float* __restrict__ bhh,   // [512] f32
    unsigned short* __restrict__ th) // [B][T][NOTES][H] bf16 (ws)
{
    __shared__ float sG[G4_ * 20];          // gate acc, [col 512][row 16 + pad 4]
    __shared__ unsigned short sH[MBLK * 136];

    const int tid  = threadIdx.x;
    const int wave = tid >> 6, lane = tid & 63;
    const int m16  = lane & 15, quad = lane >> 4;
    const int seq0 = blockIdx.x * MBLK;
    const int ncol0 = wave * 32;            // wave w owns gate cols [32w, 32w+32)

    for (int i = tid; i < MBLK * 136; i += 1024) sH[i] = 0;   // h0 = 0

    // ---- weight B-fragments (f32 -> bf16), 14 frags/wave ----
    short8 wf[3][2];   // Wih: K padded 80 -> 96
    short8 hf[4][2];   // Whh: K = 128
    #pragma unroll
    for (int nt = 0; nt < 2; ++nt) {
        const int n = ncol0 + nt * 16 + m16;
        #pragma unroll
        for (int kt = 0; kt < 3; ++kt) {
            const int k = kt * 32 + quad * 8;
            if (k < IN_) wf[kt][nt] = pack8(Wih + n * IN_ + k);
            else         wf[kt][nt] = (short8){0,0,0,0,0,0,0,0};
        }
        #pragma unroll
        for (int kt = 0; kt < 4; ++kt) {
            const int k = kt * 32 + quad * 8;
            hf[kt][nt] = pack8(Whh + n * H_ + k);
        }
    }

    // ---- elementwise mapping: thread owns h-col j, rows mb, mb+1 ----
    const int j  = tid & 127;
    const int mb = (tid >> 7) * 2;
    const float b_i = bih[      j] + bhh[      j];
    const float b_f = bih[128 + j] + bhh[128 + j];
    const float b_g = bih[256 + j] + bhh[256 + j];
    const float b_o = bih[384 + j] + bhh[384 + j];
    float    cst[2] = {0.f, 0.f};
    unsigned obase[2];
    #pragma unroll
    for (int mm = 0; mm < 2; ++mm) {
        const int sq = seq0 + mb + mm;
        const int bb = sq / NOTES_;
        const int nn = sq - bb * NOTES_;
        obase[mm] = (unsigned)bb * (T_ * NOTES_ * H_) + (unsigned)nn * H_ + (unsigned)j;
    }

    const float* xrf = XB16 ? nullptr
        : ((const float*)xin + (size_t)(seq0 + m16) * T_ * IN_);
    const unsigned short* xrb = XB16
        ? ((const unsigned short*)xin + (size_t)(seq0 + m16) * T_ * IN_) : nullptr;

    short8 ax0, ax1, ax2;
    const short8 zero8 = (short8){0,0,0,0,0,0,0,0};
    // load x(0)
    if (XB16) {
        const unsigned short* p = xrb;
        ax0 = *(const short8*)(p + quad * 8);
        ax1 = *(const short8*)(p + 32 + quad * 8);
        ax2 = (quad < 2) ? *(const short8*)(p + 64 + quad * 8) : zero8;
    } else {
        const float* p = xrf;
        ax0 = pack8(p + quad * 8);
        ax1 = pack8(p + 32 + quad * 8);
        ax2 = (quad < 2) ? pack8(p + 64 + quad * 8) : zero8;
    }

    __syncthreads();

    for (int t = 0; t < T_; ++t) {
        // A-fragments for h (guarded by barrier#2 of previous iteration)
        short8 ah[4];
        #pragma unroll
        for (int kt = 0; kt < 4; ++kt)
            ah[kt] = *(const short8*)(sH + m16 * 136 + kt * 32 + quad * 8);

        f32x4 acc[2];
        #pragma unroll
        for (int nt = 0; nt < 2; ++nt) {
            acc[nt] = (f32x4){0.f, 0.f, 0.f, 0.f};
            acc[nt] = __builtin_amdgcn_mfma_f32_16x16x32_bf16(ax0, wf[0][nt], acc[nt], 0, 0, 0);
            acc[nt] = __builtin_amdgcn_mfma_f32_16x16x32_bf16(ax1, wf[1][nt], acc[nt], 0, 0, 0);
            acc[nt] = __builtin_amdgcn_mfma_f32_16x16x32_bf16(ax2, wf[2][nt], acc[nt], 0, 0, 0);
            #pragma unroll
            for (int kt = 0; kt < 4; ++kt)
                acc[nt] = __builtin_amdgcn_mfma_f32_16x16x32_bf16(ah[kt], hf[kt][nt], acc[nt], 0, 0, 0);
        }

        // C/D layout: col = lane&15, row = quad*4 + reg
        #pragma unroll
        for (int nt = 0; nt < 2; ++nt) {
            const int c = ncol0 + nt * 16 + m16;
            *(f32x4*)(sG + c * 20 + quad * 4) = acc[nt];
        }

        // prefetch x(t+1) — issued now, consumed next iteration; its drain at
        // barrier#1 overlaps this step's remaining work
        if (t + 1 < T_) {
            if (XB16) {
                const unsigned short* p = xrb + (t + 1) * IN_;
                ax0 = *(const short8*)(p + quad * 8);
                ax1 = *(const short8*)(p + 32 + quad * 8);
                if (quad < 2) ax2 = *(const short8*)(p + 64 + quad * 8);
            } else {
                const float* p = xrf + (t + 1) * IN_;
                ax0 = pack8(p + quad * 8);
                ax1 = pack8(p + 32 + quad * 8);
                if (quad < 2) ax2 = pack8(p + 64 + quad * 8);
            }
        }

        __syncthreads();   // barrier#1: gates visible

        float2 vi = *(const float2*)(sG + (0   + j) * 20 + mb);
        float2 vf = *(const float2*)(sG + (128 + j) * 20 + mb);
        float2 vg = *(const float2*)(sG + (256 + j) * 20 + mb);
        float2 vo = *(const float2*)(sG + (384 + j) * 20 + mb);
        unsigned short hv[2];
        #pragma unroll
        for (int mm = 0; mm < 2; ++mm) {
            const float gi = (mm ? vi.y : vi.x) + b_i;
            const float gf = (mm ? vf.y : vf.x) + b_f;
            const float gg = (mm ? vg.y : vg.x) + b_g;
            const float go = (mm ? vo.y : vo.x) + b_o;
            const float cf = sigm(gf) * cst[mm] + sigm(gi) * tanh_(gg);
            cst[mm] = cf;
            const float h = sigm(go) * tanh_(cf);
            hv[mm] = f2bf(h);
            sH[(mb + mm) * 136 + j] = hv[mm];
        }

        __syncthreads();   // barrier#2: h visible

        // th store AFTER barrier#2: its vmcnt drain lands at next barrier#1,
        // overlapped with the next step's MFMA phase.
        th[obase[0] + (unsigned)t * (NOTES_ * H_)] = hv[0];
        th[obase[1] + (unsigned)t * (NOTES_ * H_)] = hv[1];
    }
}

// ---------------------------------------------------------------------------
// Phase C (MFMA): Gn[row][g] = th[row]·Wih_n[g] + bih_n[g] + bhh_n[g]
// One 16-row tile per 4 MFMAs; 832 blocks x 4 waves x 6 tiles = 19968 tiles.
// ---------------------------------------------------------------------------
__global__ __launch_bounds__(256) void gn_kernel(
    const unsigned short* __restrict__ th,    // [NROWS][128] bf16
    const float* __restrict__ Wih,            // [8][128] f32
    const float* __restrict__ bih,            // [8] f32
    const float* __restrict__ bhh,            // [8] f32
    float* __restrict__ Gn)                   // [NROWS][8] f32
{
    const int tid  = threadIdx.x;
    const int wave = tid >> 6, lane = tid & 63;
    const int m16  = lane & 15, quad = lane >> 4;
    const int wid  = blockIdx.x * 4 + wave;

    const short8 zero8 = (short8){0,0,0,0,0,0,0,0};
    short8 bw[4];   // B[k][n]: n = m16 (gate, 8 valid), k = kt*32 + quad*8 + j
    #pragma unroll
    for (int kt = 0; kt < 4; ++kt)
        bw[kt] = (m16 < 8) ? pack8(Wih + m16 * H_ + kt * 32 + quad * 8) : zero8;
    const float bsum = (m16 < 8) ? (bih[m16] + bhh[m16]) : 0.f;

    #pragma unroll
    for (int it = 0; it < 6; ++it) {
        const int tile = wid * 6 + it;
        const size_t r0 = (size_t)tile * 16;
        const unsigned short* ap = th + (r0 + m16) * H_ + quad * 8;
        f32x4 acc = (f32x4){0.f, 0.f, 0.f, 0.f};
        #pragma unroll
        for (int kt = 0; kt < 4; ++kt)
            acc = __builtin_amdgcn_mfma_f32_16x16x32_bf16(
                *(const short8*)(ap + kt * 32), bw[kt], acc, 0, 0, 0);
        if (m16 < 8) {
            #pragma unroll
            for (int r = 0; r < 4; ++r)
                Gn[(r0 + quad * 4 + r) * 8 + m16] = acc[r] + bsum;
        }
    }
}

// ---------------------------------------------------------------------------
// Phase D: note-LSTM recurrence on precomputed pre-activations.
// One thread per (b,t) sequence; next-n load prefetched.
// Gate order g: 0,1=i  2,3=f  4,5=g  6,7=o  (NH=2 interleaved)
// ---------------------------------------------------------------------------
__global__ __launch_bounds__(128) void note_out_kernel(
    const float* __restrict__ Gn,    // [SEQ2_][NOTES][8] f32
    const float* __restrict__ Whh,   // [8][2] f32
    float* __restrict__ out)         // [B][T][156] f32
{
    const int q = blockIdx.x * 128 + threadIdx.x;
    if (q >= SEQ2_) return;

    float w0[8], w1[8];
    #pragma unroll
    for (int g = 0; g < 8; ++g) { w0[g] = Whh[g * 2]; w1[g] = Whh[g * 2 + 1]; }

    const float* gp = Gn + (size_t)q * (NOTES_ * 8);
    float* op = out + (size_t)q * (NOTES_ * 2);

    float h0 = 0.f, h1 = 0.f, c0 = 0.f, c1 = 0.f;
    f32x4 ga = *(const f32x4*)(gp);
    f32x4 gb = *(const f32x4*)(gp + 4);
    for (int n = 0; n < NOTES_; ++n) {
        f32x4 na, nb;
        if (n + 1 < NOTES_) {
            na = *(const f32x4*)(gp + (n + 1) * 8);
            nb = *(const f32x4*)(gp + (n + 1) * 8 + 4);
        }
        const float i0 = ga[0] + w0[0] * h0 + w1[0] * h1;
        const float i1 = ga[1] + w0[1] * h0 + w1[1] * h1;
        const float f0 = ga[2] + w0[2] * h0 + w1[2] * h1;
        const float f1 = ga[3] + w0[3] * h0 + w1[3] * h1;
        const float g0 = gb[0] + w0[4] * h0 + w1[4] * h1;
        const float g1 = gb[1] + w0[5] * h0 + w1[5] * h1;
        const float o0 = gb[2] + w0[6] * h0 + w1[6] * h1;
        const float o1 = gb[3] + w0[7] * h0 + w1[7] * h1;
        c0 = sigm(f0) * c0 + sigm(i0) * tanh_(g0);
        c1 = sigm(f1) * c1 + sigm(i1) * tanh_(g1);
        h0 = sigm(o0) * tanh_(c0);
        h1 = sigm(o1) * tanh_(c1);
        op[n * 2 + 0] = h0;
        op[n * 2 + 1] = h1;
        ga = na; gb = nb;
    }
}

extern "C" void kernel_launch(void* const* d_in, const int* in_sizes, int n_in,
                              void* d_out, int out_size, void* d_ws, size_t ws_size,
                              hipStream_t stream) {
    const float* x     = (const float*)d_in[0];
    const float* Wih_t = (const float*)d_in[1];
    const float* Whh_t = (const float*)d_in[2];
    const float* bih_t = (const float*)d_in[3];
    const float* bhh_t = (const float*)d_in[4];
    const float* Wih_n = (const float*)d_in[5];
    const float* Whh_n = (const float*)d_in[6];
    const float* bih_n = (const float*)d_in[7];
    const float* bhh_n = (const float*)d_in[8];
    float* out = (float*)d_out;

    const size_t xb_bytes = (size_t)NSEQ_ * T_ * IN_ * 2;   // 51.1 MB
    const size_t th_bytes = (size_t)NROWS * H_ * 2;         // 81.8 MB

    if (ws_size >= xb_bytes + th_bytes) {
        // Layout: [xb16 51.1MB][th 81.8MB]; Gn (10.2MB) aliases xb16 (dead
        // after time_lstm).
        unsigned short* xb = (unsigned short*)d_ws;
        unsigned short* th = (unsigned short*)((char*)d_ws + xb_bytes);
        float* Gn = (float*)d_ws;
        xcvt_kernel<<<(XN8 + 255) / 256, 256, 0, stream>>>(x, xb);
        time_lstm_kernel<true><<<NBLK1, 1024, 0, stream>>>(
            xb, Wih_t, Whh_t, bih_t, bhh_t, th);
        gn_kernel<<<832, 256, 0, stream>>>(th, Wih_n, bih_n, bhh_n, Gn);
        note_out_kernel<<<SEQ2_ / 128, 128, 0, stream>>>(Gn, Whh_n, out);
    } else {
        // Fallback: no x pre-convert. [th 81.8MB][Gn 10.2MB]
        unsigned short* th = (unsigned short*)d_ws;
        float* Gn = (float*)((char*)d_ws + th_bytes);
        time_lstm_kernel<false><<<NBLK1, 1024, 0, stream>>>(
            x, Wih_t, Whh_t, bih_t, bhh_t, th);
        gn_kernel<<<832, 256, 0, stream>>>(th, Wih_n, bih_n, bhh_n, Gn);
        note_out_kernel<<<SEQ2_ / 128, 128, 0, stream>>>(Gn, Whh_n, out);
    }
}